// Round 4
// baseline (550.448 us; speedup 1.0000x reference)
//
#include <hip/hip_runtime.h>
#include <hip/hip_bf16.h>
#include <math.h>

#define G_ 32
#define H_ 12
#define D_ 768
#define HD_ 64
#define FF_ 3072
#define B_ 2
#define T_ 2048
#define SPAN_ 63
#define SPANC_ 129
#define EPSF 1e-5f

// zero-slot sentinels for the packed bias table
#define REL_ZOFF 47628   // 3969*12 (valid rel offsets are pre-multiplied by 12, max 47616)
#define DEMO_ZIDX 8127   // valid demo idx max 8126
#define RELZ_N ((3969 + 1) * 12)   // 47640 floats
#define DEMOZ_N ((8127 + 1) * 12)  // 97536 floats

typedef short bf16x8 __attribute__((ext_vector_type(8)));
typedef short short4v __attribute__((ext_vector_type(4)));
typedef float f32x4 __attribute__((ext_vector_type(4)));

__device__ __forceinline__ short f2bf(float f) {
    unsigned u = __builtin_bit_cast(unsigned, f);
    u = u + 0x7FFFu + ((u >> 16) & 1u);
    return (short)(u >> 16);
}

// ---------------- LayerNorm (f32 in -> bf16 out): one wave per row ----------------
__global__ __launch_bounds__(256) void ln_bf16_kernel(const float* __restrict__ x,
                                                      const float* __restrict__ w,
                                                      const float* __restrict__ b,
                                                      short* __restrict__ out) {
    int wv = threadIdx.x >> 6;
    int lane = threadIdx.x & 63;
    int rowi = blockIdx.x * 4 + wv;
    const float* xr = x + (size_t)rowi * D_;
    float vals[12];
    float s = 0.f;
#pragma unroll
    for (int i = 0; i < 12; ++i) { vals[i] = xr[lane + i * 64]; s += vals[i]; }
#pragma unroll
    for (int off = 32; off > 0; off >>= 1) s += __shfl_xor(s, off, 64);
    float mean = s * (1.0f / D_);
    float vs = 0.f;
#pragma unroll
    for (int i = 0; i < 12; ++i) { float d = vals[i] - mean; vs += d * d; }
#pragma unroll
    for (int off = 32; off > 0; off >>= 1) vs += __shfl_xor(vs, off, 64);
    float rstd = rsqrtf(vs * (1.0f / D_) + EPSF);
    short* outr = out + (size_t)rowi * D_;
#pragma unroll
    for (int i = 0; i < 12; ++i) {
        int c = lane + i * 64;
        outr[c] = f2bf((vals[i] - mean) * rstd * w[c] + b[c]);
    }
}

// ---------------- transpose-cast: W [K][N] f32 -> Wt [N][K] bf16 ----------------
__global__ __launch_bounds__(256) void tcast_kernel(const float* __restrict__ W,
                                                    short* __restrict__ Wt,
                                                    int K, int N) {
    __shared__ float t[32][33];
    int n0 = blockIdx.x * 32, k0 = blockIdx.y * 32;
    int tid = threadIdx.x;
    int r = tid >> 3, c4 = (tid & 7) * 4;
    float4 v = *(const float4*)(W + (size_t)(k0 + r) * N + n0 + c4);
    t[r][c4 + 0] = v.x; t[r][c4 + 1] = v.y; t[r][c4 + 2] = v.z; t[r][c4 + 3] = v.w;
    __syncthreads();
    short4v o;
    o[0] = f2bf(t[c4 + 0][r]); o[1] = f2bf(t[c4 + 1][r]);
    o[2] = f2bf(t[c4 + 2][r]); o[3] = f2bf(t[c4 + 3][r]);
    *(short4v*)(Wt + (size_t)(n0 + r) * K + k0 + c4) = o;
}

// ---------------- pad-copy: dst[0..nsrc)=src, [nsrc..ntot)=0 ----------------
__global__ __launch_bounds__(256) void padcopy_kernel(const float* __restrict__ src,
                                                      float* __restrict__ dst,
                                                      int nsrc, int ntot) {
    int i = blockIdx.x * 256 + threadIdx.x;
    if (i < ntot) dst[i] = (i < nsrc) ? src[i] : 0.f;
}

// ---------------- packed bias-index table: packed[q][k] ----------------
__global__ __launch_bounds__(256) void pack_kernel(const int* __restrict__ rowp,
                                                   const int* __restrict__ colp,
                                                   const int* __restrict__ drowp,
                                                   const int* __restrict__ dcolp,
                                                   const int* __restrict__ didp,
                                                   unsigned* __restrict__ packed) {
    int idx = blockIdx.x * 256 + threadIdx.x;  // [0, T*T)
    int q = idx >> 11, k = idx & (T_ - 1);
    int idq = didp[q], idk = didp[k];
    bool valid = (idq >= 0) && (idk >= 0);
    unsigned rel = REL_ZOFF, dem = DEMO_ZIDX;
    if (valid) {
        int dr = min(max(rowp[q] - rowp[k], -(G_ - 1)), G_ - 1) + (G_ - 1);
        int dc = min(max(colp[q] - colp[k], -(G_ - 1)), G_ - 1) + (G_ - 1);
        rel = (unsigned)(dr * SPAN_ + dc) * 12u;
        if (idq == idk) {
            int ddr = min(max(drowp[q] - drowp[k], -(G_ - 1)), G_ - 1) + (G_ - 1);
            int ddc = min(max(dcolp[q] - dcolp[k], -2 * G_), 2 * G_) + 2 * G_;
            dem = (unsigned)(ddr * SPANC_ + ddc);
        }
    }
    packed[idx] = rel | (dem << 16);
}

// ---------------- bf16 MFMA GEMM: C = A[M][K] * Bt[N][K]^T ----------------
enum { EPI_NONE = 0, EPI_RES = 1, EPI_GELU = 2 };

template <int EPI, int BF16OUT>
__global__ __launch_bounds__(256, 2) void gemm_bf16(const short* __restrict__ A,
                                                    const short* __restrict__ Bt,
                                                    const float* __restrict__ bias,
                                                    const float* __restrict__ res,
                                                    void* __restrict__ Cv,
                                                    int M, int N, int K) {
    __shared__ short As[128 * 64];
    __shared__ short Bs[128 * 64];
    int tid = threadIdx.x;
    int l = tid & 63;
    int w = tid >> 6;
    int wm = w >> 1, wn = w & 1;
    int row0 = blockIdx.y * 128, col0 = blockIdx.x * 128;
    int g = l >> 4, c16 = l & 15;
    f32x4 zero = {0.f, 0.f, 0.f, 0.f};
    f32x4 acc[4][4];
#pragma unroll
    for (int m = 0; m < 4; ++m)
#pragma unroll
        for (int n = 0; n < 4; ++n) acc[m][n] = zero;

    for (int k0 = 0; k0 < K; k0 += 64) {
#pragma unroll
        for (int p = 0; p < 4; ++p) {
            int sidx = p * 256 + tid;
            int row = sidx >> 3, cseg = sidx & 7;
            int ds = row * 64 + ((cseg ^ (row & 7)) << 3);
            *(bf16x8*)&As[ds] = *(const bf16x8*)(A + (size_t)(row0 + row) * K + k0 + cseg * 8);
            *(bf16x8*)&Bs[ds] = *(const bf16x8*)(Bt + (size_t)(col0 + row) * K + k0 + cseg * 8);
        }
        __syncthreads();
#pragma unroll
        for (int dk = 0; dk < 2; ++dk) {
            bf16x8 af[4], bfr[4];
#pragma unroll
            for (int m = 0; m < 4; ++m) {
                int r = wm * 64 + m * 16 + c16;
                af[m] = *(const bf16x8*)&As[r * 64 + (((dk * 4 + g) ^ (r & 7)) << 3)];
            }
#pragma unroll
            for (int n = 0; n < 4; ++n) {
                int r = wn * 64 + n * 16 + c16;
                bfr[n] = *(const bf16x8*)&Bs[r * 64 + (((dk * 4 + g) ^ (r & 7)) << 3)];
            }
#pragma unroll
            for (int m = 0; m < 4; ++m)
#pragma unroll
                for (int n = 0; n < 4; ++n)
                    acc[m][n] = __builtin_amdgcn_mfma_f32_16x16x32_bf16(af[m], bfr[n], acc[m][n], 0, 0, 0);
        }
        __syncthreads();
    }

#pragma unroll
    for (int m = 0; m < 4; ++m)
#pragma unroll
        for (int n = 0; n < 4; ++n) {
            int rrow = row0 + wm * 64 + m * 16 + g * 4;
            int ccol = col0 + wn * 64 + n * 16 + c16;
            float bv = bias[ccol];
#pragma unroll
            for (int i = 0; i < 4; ++i) {
                float v = acc[m][n][i] + bv;
                if (EPI == EPI_GELU) v = 0.5f * v * (1.f + erff(v * 0.70710678118f));
                if (EPI == EPI_RES) v += res[(size_t)(rrow + i) * N + ccol];
                if (BF16OUT)
                    ((short*)Cv)[(size_t)(rrow + i) * N + ccol] = f2bf(v);
                else
                    ((float*)Cv)[(size_t)(rrow + i) * N + ccol] = v;
            }
        }
}

// ---------------- fused MFMA flash attention, table-driven bias ----------------
// Block: 256 thr (4 waves), QBLK=64 (wave w owns q-rows w*16..+15), KBLK=64.
__global__ __launch_bounds__(256, 2) void attn_mfma(
    const short* __restrict__ qkv,
    const unsigned* __restrict__ packed,
    const float* __restrict__ relz, const float* __restrict__ demoz,
    short* __restrict__ attn_o) {
    __shared__ short Ks[64 * 64];     // XOR-seg swizzled (by row&7)
    __shared__ short Vt[64 * 72];     // V^T [d][k], k-chunk XOR-swizzled by d>>3
    __shared__ short Pb[4][16 * 72];  // per-wave P, k-chunk XOR-swizzled by q>>2

    int tid = threadIdx.x, w = tid >> 6, l = tid & 63;
    int g = l >> 4, c16 = l & 15;
    int qt = blockIdx.x & 31, bh = blockIdx.x >> 5;
    int h = bh % H_, b = bh / H_;
    int q0 = qt * 64;
    const int QS = 3 * D_;

    // Q fragments (A-operand: row = lane&15, k contiguous per group)
    bf16x8 qf[2];
    {
        int qrow = q0 + w * 16 + c16;
        const short* qp = qkv + (size_t)(b * T_ + qrow) * QS + h * HD_;
#pragma unroll
        for (int dk = 0; dk < 2; ++dk) qf[dk] = *(const bf16x8*)(qp + dk * 32 + g * 8);
    }
    // packed-table row base for each of this lane's 4 q-rows
    const unsigned* prow[4];
#pragma unroll
    for (int i = 0; i < 4; ++i)
        prow[i] = packed + (size_t)(q0 + w * 16 + g * 4 + i) * T_;

    f32x4 zero = {0.f, 0.f, 0.f, 0.f};
    f32x4 oacc[4];
#pragma unroll
    for (int nf = 0; nf < 4; ++nf) oacc[nf] = zero;
    float mrun[4], lrun[4];
#pragma unroll
    for (int i = 0; i < 4; ++i) { mrun[i] = -INFINITY; lrun[i] = 0.f; }

    for (int kb = 0; kb < T_; kb += 64) {
        // ---- stage K (seg-swizzled) ----
#pragma unroll
        for (int p = 0; p < 2; ++p) {
            int sidx = p * 256 + tid;
            int row = sidx >> 3, cseg = sidx & 7;
            *(bf16x8*)&Ks[row * 64 + ((cseg ^ (row & 7)) << 3)] =
                *(const bf16x8*)(qkv + (size_t)(b * T_ + kb + row) * QS + D_ + h * HD_ + cseg * 8);
        }
        // ---- stage V^T with chunk swizzle: slot(k) = ((k>>3)^(d>>3))*8 + (k&7) ----
        {
            int vrow = tid >> 2, part = tid & 3;
            const short* vp = qkv + (size_t)(b * T_ + kb + vrow) * QS + 2 * D_ + h * HD_ + part * 16;
            bf16x8 v0 = *(const bf16x8*)(vp);
            bf16x8 v1 = *(const bf16x8*)(vp + 8);
            int kchunk = vrow >> 3, kpos = vrow & 7;
#pragma unroll
            for (int j = 0; j < 8; ++j) {
                int d = part * 16 + j;
                Vt[d * 72 + (((kchunk ^ (d >> 3)) & 7) << 3) + kpos] = v0[j];
            }
#pragma unroll
            for (int j = 0; j < 8; ++j) {
                int d = part * 16 + 8 + j;
                Vt[d * 72 + (((kchunk ^ (d >> 3)) & 7) << 3) + kpos] = v1[j];
            }
        }
        __syncthreads();

        // ---- QK^T ----
        f32x4 sac[4];
#pragma unroll
        for (int nf = 0; nf < 4; ++nf) sac[nf] = zero;
#pragma unroll
        for (int dk = 0; dk < 2; ++dk) {
#pragma unroll
            for (int nf = 0; nf < 4; ++nf) {
                int r = nf * 16 + c16;
                bf16x8 kf = *(const bf16x8*)&Ks[r * 64 + (((dk * 4 + g) ^ (r & 7)) << 3)];
                sac[nf] = __builtin_amdgcn_mfma_f32_16x16x32_bf16(qf[dk], kf, sac[nf], 0, 0, 0);
            }
        }

        // ---- bias via packed table (lane holds S[q=g*4+i][k=nf*16+c16]) ----
        float st[4][4];
        float rmax[4] = {-INFINITY, -INFINITY, -INFINITY, -INFINITY};
#pragma unroll
        for (int nf = 0; nf < 4; ++nf) {
            int kk = kb + nf * 16 + c16;
#pragma unroll
            for (int i = 0; i < 4; ++i) {
                unsigned t = prow[i][kk];
                float bias = relz[(t & 0xFFFFu) + h] + demoz[(t >> 16) * 12u + h];
                float sv = fmaf(sac[nf][i], 0.125f, bias);
                st[nf][i] = sv;
                rmax[i] = fmaxf(rmax[i], sv);
            }
        }
        // ---- online softmax (row spread across 16 lanes of same group) ----
#pragma unroll
        for (int i = 0; i < 4; ++i) {
#pragma unroll
            for (int off = 1; off < 16; off <<= 1)
                rmax[i] = fmaxf(rmax[i], __shfl_xor(rmax[i], off, 64));
        }
        float pp[4][4];
#pragma unroll
        for (int i = 0; i < 4; ++i) {
            float newm = fmaxf(mrun[i], rmax[i]);
            float sf = __expf(mrun[i] - newm);
            mrun[i] = newm;
            float ls = 0.f;
#pragma unroll
            for (int nf = 0; nf < 4; ++nf) {
                float e = __expf(st[nf][i] - newm);
                pp[nf][i] = e;
                ls += e;
            }
#pragma unroll
            for (int off = 1; off < 16; off <<= 1) ls += __shfl_xor(ls, off, 64);
            lrun[i] = lrun[i] * sf + ls;
#pragma unroll
            for (int nf = 0; nf < 4; ++nf) oacc[nf][i] *= sf;
        }
        // ---- P -> wave-private LDS (chunk-swizzled by q>>2 == g) ----
        short* pbw = &Pb[w][0];
#pragma unroll
        for (int nf = 0; nf < 4; ++nf) {
            int chunkbase = nf * 2 + (c16 >> 3);
            int kpos = c16 & 7;
#pragma unroll
            for (int i = 0; i < 4; ++i)
                pbw[(g * 4 + i) * 72 + (((chunkbase ^ g) & 7) << 3) + kpos] = f2bf(pp[nf][i]);
        }
        // ---- PV ----
#pragma unroll
        for (int dk = 0; dk < 2; ++dk) {
            bf16x8 pa = *(const bf16x8*)&pbw[c16 * 72 + (((dk * 4 + g) ^ (c16 >> 2)) & 7) * 8];
#pragma unroll
            for (int nf = 0; nf < 4; ++nf) {
                int d = nf * 16 + c16;
                bf16x8 vb = *(const bf16x8*)&Vt[d * 72 + (((dk * 4 + g) ^ (d >> 3)) & 7) * 8];
                oacc[nf] = __builtin_amdgcn_mfma_f32_16x16x32_bf16(pa, vb, oacc[nf], 0, 0, 0);
            }
        }
        __syncthreads();
    }

    // ---- finalize ----
#pragma unroll
    for (int nf = 0; nf < 4; ++nf)
#pragma unroll
        for (int i = 0; i < 4; ++i) {
            float o = oacc[nf][i] / lrun[i];
            int qq = q0 + w * 16 + g * 4 + i;
            attn_o[(size_t)(b * T_ + qq) * D_ + h * HD_ + nf * 16 + c16] = f2bf(o);
        }
}

// ---------------- launcher ----------------
extern "C" void kernel_launch(void* const* d_in, const int* in_sizes, int n_in,
                              void* d_out, int out_size, void* d_ws, size_t ws_size,
                              hipStream_t stream) {
    const float* x = (const float*)d_in[0];
    const int* rowp = (const int*)d_in[1];
    const int* colp = (const int*)d_in[2];
    const int* drowp = (const int*)d_in[3];
    const int* dcolp = (const int*)d_in[4];
    const int* didp = (const int*)d_in[5];
    // d_in[6] = is_sep (bool) — unused: is_sep <=> demo_id < 0 by construction
    const float* ln1_w = (const float*)d_in[7];
    const float* ln1_b = (const float*)d_in[8];
    const float* ln2_w = (const float*)d_in[9];
    const float* ln2_b = (const float*)d_in[10];
    const float* qkv_w = (const float*)d_in[11];
    const float* qkv_b = (const float*)d_in[12];
    const float* proj_w = (const float*)d_in[13];
    const float* proj_b = (const float*)d_in[14];
    const float* ff1_w = (const float*)d_in[15];
    const float* ff1_b = (const float*)d_in[16];
    const float* ff2_w = (const float*)d_in[17];
    const float* ff2_b = (const float*)d_in[18];
    const float* rel_emb = (const float*)d_in[19];
    const float* demo_emb = (const float*)d_in[20];
    float* out = (float*)d_out;

    const int M = B_ * T_;  // 4096
    char* p = (char*)d_ws;
    short* h1 = (short*)p;     p += (size_t)M * D_ * 2;
    short* qkvb = (short*)p;   p += (size_t)M * 3 * D_ * 2;
    short* attn_o = (short*)p; p += (size_t)M * D_ * 2;
    float* x2 = (float*)p;     p += (size_t)M * D_ * 4;
    short* h2 = (short*)p;     p += (size_t)M * D_ * 2;
    char* ffact_base = p;      p += (size_t)M * FF_ * 2;   // 25.2 MB region
    short* qkvt = (short*)p;   p += (size_t)(3 * D_) * D_ * 2;
    short* projt = (short*)p;  p += (size_t)D_ * D_ * 2;
    short* ff1t = (short*)p;   p += (size_t)FF_ * D_ * 2;
    short* ff2t = (short*)p;   p += (size_t)D_ * FF_ * 2;

    // bias table aliases the ffact region (ffact written only after attention)
    short* ffact = (short*)ffact_base;
    unsigned* packed = (unsigned*)ffact_base;                       // 16 MB
    float* relz = (float*)(ffact_base + (size_t)T_ * T_ * 4);       // 190.6 KB
    float* demoz = relz + RELZ_N;                                   // 390.1 KB

    // ---- precompute ----
    tcast_kernel<<<dim3(3 * D_ / 32, D_ / 32), 256, 0, stream>>>(qkv_w, qkvt, D_, 3 * D_);
    tcast_kernel<<<dim3(D_ / 32, D_ / 32), 256, 0, stream>>>(proj_w, projt, D_, D_);
    tcast_kernel<<<dim3(FF_ / 32, D_ / 32), 256, 0, stream>>>(ff1_w, ff1t, D_, FF_);
    tcast_kernel<<<dim3(D_ / 32, FF_ / 32), 256, 0, stream>>>(ff2_w, ff2t, FF_, D_);
    padcopy_kernel<<<dim3((RELZ_N + 255) / 256), 256, 0, stream>>>(rel_emb, relz, SPAN_ * SPAN_ * H_, RELZ_N);
    padcopy_kernel<<<dim3((DEMOZ_N + 255) / 256), 256, 0, stream>>>(demo_emb, demoz, SPANC_ * SPAN_ * H_, DEMOZ_N);
    pack_kernel<<<dim3(T_ * T_ / 256), 256, 0, stream>>>(rowp, colp, drowp, dcolp, didp, packed);

    // ---- main pipeline ----
    ln_bf16_kernel<<<dim3(M / 4), 256, 0, stream>>>(x, ln1_w, ln1_b, h1);

    gemm_bf16<EPI_NONE, 1><<<dim3(3 * D_ / 128, M / 128), 256, 0, stream>>>(
        h1, qkvt, qkv_b, nullptr, qkvb, M, 3 * D_, D_);

    attn_mfma<<<dim3(B_ * H_ * (T_ / 64)), 256, 0, stream>>>(
        qkvb, packed, relz, demoz, attn_o);

    gemm_bf16<EPI_RES, 0><<<dim3(D_ / 128, M / 128), 256, 0, stream>>>(
        attn_o, projt, proj_b, x, x2, M, D_, D_);

    ln_bf16_kernel<<<dim3(M / 4), 256, 0, stream>>>(x2, ln2_w, ln2_b, h2);

    gemm_bf16<EPI_GELU, 1><<<dim3(FF_ / 128, M / 128), 256, 0, stream>>>(
        h2, ff1t, ff1_b, nullptr, ffact, M, FF_, D_);

    gemm_bf16<EPI_RES, 0><<<dim3(D_ / 128, M / 128), 256, 0, stream>>>(
        ffact, ff2t, ff2_b, x2, out, M, D_, FF_);
}